// Round 16
// baseline (131.703 us; speedup 1.0000x reference)
//
#include <hip/hip_runtime.h>

#define V_CNT   10475
#define N3      31425      // V*3
#define NPAD    31488      // 328*96
#define J_CNT   55
#define NBETA   10
#define KP      512        // padded K for GEMM1 (486 pf + 10 betas + 1 vt + pad)
#define NFRAMES 512
#define BM      64         // frames per block
#define BNC     96         // columns (verts*3) per block (32 verts)
#define VTILES  328
#define FTILES  8
#define RPK_BLOCKS (492 * 8)   // (NPAD/64) x (KP/64)

typedef __attribute__((ext_vector_type(8))) __bf16 bf16x8;
typedef __attribute__((ext_vector_type(8))) unsigned short ushort8;
typedef __attribute__((ext_vector_type(4))) float f32x4;

__device__ __forceinline__ unsigned short f2bf(float f) {
    unsigned u = __float_as_uint(f);
    u += 0x7fff + ((u >> 16) & 1);
    return (unsigned short)(u >> 16);
}
__device__ __forceinline__ float bf2f(unsigned short s) {
    return __uint_as_float(((unsigned)s) << 16);
}
// global -> LDS direct 16B load. LDS dest must be wave-uniform; lane writes base+lane*16.
__device__ __forceinline__ void gl_lds16(const void* g, void* l) {
    auto gp = (const __attribute__((address_space(1))) unsigned int*)(uintptr_t)g;
    auto lp = (__attribute__((address_space(3))) unsigned int*)(unsigned int)(uintptr_t)l;
    __builtin_amdgcn_global_load_lds(gp, lp, 16, 0, 0);
}

__device__ __constant__ int c_parents[J_CNT] = {
    -1, 0, 0, 0, 1, 2, 3, 4, 5, 6, 7, 8, 9, 9, 9, 12, 13, 14, 16, 17, 18, 19,
    15, 15, 15,
    20, 25, 26, 20, 28, 29, 20, 31, 32, 20, 34, 35, 20, 37, 38,
    21, 40, 41, 21, 43, 44, 21, 46, 47, 21, 49, 50, 21, 52, 53};

// ---------------- prep: repack (blocks [0,RPK_BLOCKS)) + skel (next NFRAMES blocks) -------
__global__ __launch_bounds__(256) void prep_kernel(
    const float* __restrict__ posedirs, const float* __restrict__ shapedirs,
    const float* __restrict__ v_template, unsigned short* __restrict__ B_pack,
    const float* __restrict__ body_pose, const float* __restrict__ betas,
    const float* __restrict__ global_orient, const float* __restrict__ J_template,
    const float* __restrict__ J_shapedirs, const float* __restrict__ odp,
    unsigned short* __restrict__ pf_ext, unsigned short* __restrict__ A_bf)
{
    const int rb = blockIdx.x;
    const int tid = threadIdx.x;

    __shared__ float R_s[J_CNT][9];
    __shared__ float j_s[J_CNT][3];
    __shared__ float G_s[J_CNT][12];

    if (rb < RPK_BLOCKS) {
        const int n0 = (rb % 492) * 64;
        const int k0 = (rb / 492) * 64;
        const int nl = tid >> 2;
        const int kh = tid & 3;
        const int ng = n0 + nl;
        ushort8 v0, v1;
#pragma unroll
        for (int j = 0; j < 16; j++) {
            int kgl = k0 + kh * 16 + j;
            float v = 0.0f;
            if (ng < N3) {
                if (kgl < 486)       v = posedirs[(size_t)kgl * N3 + ng];
                else if (kgl < 496)  v = shapedirs[ng * NBETA + (kgl - 486)];
                else if (kgl == 496) v = v_template[ng];
            }
            if (j < 8) v0[j] = f2bf(v);
            else       v1[j - 8] = f2bf(v);
        }
        unsigned short* dst = &B_pack[(size_t)(n0 + nl) * KP + k0 + kh * 16];
        *(ushort8*)(dst)     = v0;
        *(ushort8*)(dst + 8) = v1;
        return;
    }

    const int n = rb - RPK_BLOCKS;
    const int lane = tid;

    if (lane < J_CNT) {
        float aa0, aa1, aa2;
        if (lane == 0) {
            aa0 = global_orient[n * 3 + 0];
            aa1 = global_orient[n * 3 + 1];
            aa2 = global_orient[n * 3 + 2];
        } else if (lane < 22) {
            int o = n * 63 + (lane - 1) * 3;
            aa0 = body_pose[o]; aa1 = body_pose[o + 1]; aa2 = body_pose[o + 2];
        } else {
            int o = (lane - 22) * 3;
            aa0 = odp[o]; aa1 = odp[o + 1]; aa2 = odp[o + 2];
        }
        float ang = sqrtf(aa0 * aa0 + aa1 * aa1 + aa2 * aa2 + 1e-12f);
        float inv = 1.0f / ang;
        float ax = aa0 * inv, ay = aa1 * inv, az = aa2 * inv;
        float s = sinf(ang), c = cosf(ang), cc = 1.0f - c;
        float R[9];
        R[0] = c + cc * ax * ax;        R[1] = -s * az + cc * ax * ay;  R[2] = s * ay + cc * ax * az;
        R[3] = s * az + cc * ax * ay;   R[4] = c + cc * ay * ay;        R[5] = -s * ax + cc * ay * az;
        R[6] = -s * ay + cc * ax * az;  R[7] = s * ax + cc * ay * az;   R[8] = c + cc * az * az;
#pragma unroll
        for (int k = 0; k < 9; k++) R_s[lane][k] = R[k];
#pragma unroll
        for (int cd = 0; cd < 3; cd++) {
            float acc = J_template[lane * 3 + cd];
#pragma unroll
            for (int k = 0; k < NBETA; k++)
                acc += betas[n * NBETA + k] * J_shapedirs[(lane * 3 + cd) * NBETA + k];
            j_s[lane][cd] = acc;
        }
        if (lane >= 1) {
#pragma unroll
            for (int e = 0; e < 9; e++)
                pf_ext[n * KP + (lane - 1) * 9 + e] =
                    f2bf(R[e] - ((e == 0 || e == 4 || e == 8) ? 1.0f : 0.0f));
        }
    }
    if (lane == 55) {
#pragma unroll
        for (int b = 0; b < NBETA; b++) pf_ext[n * KP + 486 + b] = f2bf(betas[n * NBETA + b]);
        pf_ext[n * KP + 496] = 0x3F80;
    }
    if (lane == 56) {
        for (int k = 497; k < KP; k++) pf_ext[n * KP + k] = 0;
    }
    __syncthreads();
    if (lane == 0) {
        for (int r = 0; r < 3; r++) {
            G_s[0][r * 4 + 0] = R_s[0][r * 3 + 0];
            G_s[0][r * 4 + 1] = R_s[0][r * 3 + 1];
            G_s[0][r * 4 + 2] = R_s[0][r * 3 + 2];
            G_s[0][r * 4 + 3] = j_s[0][r];
        }
        for (int i = 1; i < J_CNT; i++) {
            int p = c_parents[i];
            float rel0 = j_s[i][0] - j_s[p][0];
            float rel1 = j_s[i][1] - j_s[p][1];
            float rel2 = j_s[i][2] - j_s[p][2];
            for (int r = 0; r < 3; r++) {
                float g0 = G_s[p][r * 4 + 0], g1 = G_s[p][r * 4 + 1], g2 = G_s[p][r * 4 + 2];
                G_s[i][r * 4 + 0] = g0 * R_s[i][0] + g1 * R_s[i][3] + g2 * R_s[i][6];
                G_s[i][r * 4 + 1] = g0 * R_s[i][1] + g1 * R_s[i][4] + g2 * R_s[i][7];
                G_s[i][r * 4 + 2] = g0 * R_s[i][2] + g1 * R_s[i][5] + g2 * R_s[i][8];
                G_s[i][r * 4 + 3] = g0 * rel0 + g1 * rel1 + g2 * rel2 + G_s[p][r * 4 + 3];
            }
        }
    }
    __syncthreads();
    if (lane < 64) {
        float vals[12];
#pragma unroll
        for (int r = 0; r < 12; r++) vals[r] = 0.0f;
        if (lane < J_CNT) {
            const float jx = j_s[lane][0], jy = j_s[lane][1], jz = j_s[lane][2];
#pragma unroll
            for (int r = 0; r < 3; r++) {
                float g0 = G_s[lane][r * 4 + 0], g1 = G_s[lane][r * 4 + 1], g2 = G_s[lane][r * 4 + 2];
                vals[r * 4 + 0] = g0;
                vals[r * 4 + 1] = g1;
                vals[r * 4 + 2] = g2;
                vals[r * 4 + 3] = G_s[lane][r * 4 + 3] - (g0 * jx + g1 * jy + g2 * jz);
            }
        }
#pragma unroll
        for (int r = 0; r < 12; r++)
            A_bf[(n * 12 + r) * 64 + lane] = f2bf(vals[r]);
    }
}

// ---------------- fused GEMM, 32-vert tiles for 3 blocks/CU ------------------------------
// R13 structure with BNC 192->96: LDS 74.7KB->44.8KB lifts occupancy 2->3 blocks/CU, and
// grid 1312->2624 smooths the tail. Pipeline machinery (counted vmcnt, sched_barrier,
// XCD co-location) unchanged. GEMM2 is R13-verbatim with nn collapsed to 1.
__global__ __launch_bounds__(256, 2) void gemm_kernel(
    const unsigned short* __restrict__ pf_ext, const unsigned short* __restrict__ B_pack,
    const unsigned short* __restrict__ A_bf, const float* __restrict__ lbs_weights,
    const float* __restrict__ transl, float* __restrict__ out)
{
    // LDS map (45824 B -> 3 blocks/CU):
    //   0     pf_b[0] 8192      [64f][128B] swizzled
    //   8192  pf_b[1] 8192
    //   16384 B_b[0] 12288      [96n][128B] swizzled
    //   28672 B_b[1] 12288
    //   40960 w_b    4096       [32v][128B] swizzled (staged post-K-loop)
    //   45056 tr_s   768
    // overlays after GEMM1 (B regions dead):
    //   vp_s = smem+16384, [64f][100] ushort (12800B, ends 29184)
    //   rst  = smem+29184, [32][100] float  (12800B, ends 41984; w_b dead at epilogue)
    __shared__ __align__(128) unsigned char smem[45824];
    unsigned char* pf_b0 = smem;
    unsigned char* pf_b1 = smem + 8192;
    unsigned char* B_b0  = smem + 16384;
    unsigned char* B_b1  = smem + 28672;
    unsigned char* w_b   = smem + 40960;
    float* tr_s          = (float*)(smem + 45056);
    unsigned short* vp_s = (unsigned short*)(smem + 16384);
    float* rst           = (float*)(smem + 29184);

    const int tid = threadIdx.x;
    const int w = tid >> 6, l = tid & 63;
    const int wm = w >> 1, wn = w & 1;         // wave tile: frames wm*32.., cols wn*48..

    // XCD co-location: 2624 blocks = 41 groups x 64; group = 8 vtiles x 8 ftiles;
    // vtile = gi&7 = bid%8 -> XCD, so a vtile's 8 ftile-blocks share an XCD.
    const int bid = blockIdx.x;
    const int group = bid >> 6, gi = bid & 63;
    const int vt = group * 8 + (gi & 7);
    const int ft = gi >> 3;
    const int f0 = ft * BM;
    const int v00 = vt * 32;
    const int n0c = vt * BNC;

    const unsigned char* pfg = (const unsigned char*)pf_ext + (size_t)f0 * (KP * 2);
    const unsigned char* Bg  = (const unsigned char*)B_pack + (size_t)n0c * (KP * 2);

    // STAGE one 128B K-chunk (ks): 2 pf + 3 B gl_lds per wave = 5 VMEM ops
#define STAGE_KS(ks, pfd, Bd)                                                              \
    {                                                                                      \
        const int kb = (ks) * 128;                                                         \
        _Pragma("unroll")                                                                  \
        for (int i = 0; i < 2; i++) {                                                      \
            int row0 = w * 16 + i * 8;                                                     \
            int row = row0 + (l >> 3);                                                     \
            const unsigned char* src = pfg + (size_t)row * (KP * 2) + kb +                 \
                                       (((l & 7) ^ (l >> 3)) * 16);                        \
            gl_lds16(src, (pfd) + row0 * 128);                                             \
        }                                                                                  \
        _Pragma("unroll")                                                                  \
        for (int i = 0; i < 3; i++) {                                                      \
            int row0 = i * 32 + w * 8;                                                     \
            int row = row0 + (l >> 3);                                                     \
            const unsigned char* src = Bg + (size_t)row * (KP * 2) + kb +                  \
                                       (((l & 7) ^ (l >> 3)) * 16);                        \
            gl_lds16(src, (Bd) + row0 * 128);                                              \
        }                                                                                  \
    }

    // -------- GEMM1: vp[f][n] = sum_k pf_ext[f][k] * B_pack[n][k] --------
    f32x4 acc[2][3];
#pragma unroll
    for (int m = 0; m < 2; m++)
#pragma unroll
        for (int nn = 0; nn < 3; nn++) acc[m][nn] = (f32x4){0.f, 0.f, 0.f, 0.f};

    STAGE_KS(0, pf_b0, B_b0);
    STAGE_KS(1, pf_b1, B_b1);
    asm volatile("s_waitcnt vmcnt(5)" ::: "memory");
    __builtin_amdgcn_sched_barrier(0);
    __builtin_amdgcn_s_barrier();

#pragma unroll
    for (int ks = 0; ks < 8; ks++) {
        unsigned char* pfc = (ks & 1) ? pf_b1 : pf_b0;
        unsigned char* Bc  = (ks & 1) ? B_b1 : B_b0;
#pragma unroll
        for (int ksub = 0; ksub < 2; ksub++) {
            bf16x8 a[2], b[3];
#pragma unroll
            for (int m = 0; m < 2; m++) {
                int f = wm * 32 + m * 16 + (l & 15);
                int off = f * 128 + ((ksub * 64 + (l >> 4) * 16) ^ ((f & 7) << 4));
                a[m] = *(const bf16x8*)(pfc + off);
            }
#pragma unroll
            for (int nn = 0; nn < 3; nn++) {
                int col = wn * 48 + nn * 16 + (l & 15);
                int off = col * 128 + ((ksub * 64 + (l >> 4) * 16) ^ ((col & 7) << 4));
                b[nn] = *(const bf16x8*)(Bc + off);
            }
#pragma unroll
            for (int m = 0; m < 2; m++)
#pragma unroll
                for (int nn = 0; nn < 3; nn++)
                    acc[m][nn] = __builtin_amdgcn_mfma_f32_16x16x32_bf16(a[m], b[nn], acc[m][nn], 0, 0, 0);
        }
        __builtin_amdgcn_sched_barrier(0);
        __builtin_amdgcn_s_barrier();
        if (ks < 6) {
            STAGE_KS(ks + 2, pfc, Bc);
        }
        if (ks < 7) {
            if (ks < 6) asm volatile("s_waitcnt vmcnt(5)" ::: "memory");
            else        asm volatile("s_waitcnt vmcnt(0)" ::: "memory");
            __builtin_amdgcn_sched_barrier(0);
            __builtin_amdgcn_s_barrier();
        }
    }
#undef STAGE_KS

    // stage lbs weights tile -> w_b [32v][64j] bf16 (XOR-swizzled chunks), transl -> tr_s
    {
        int v = tid >> 3, jg = tid & 7;
        int vg = v00 + v;
        ushort8 val;
#pragma unroll
        for (int e = 0; e < 8; e++) {
            int j = jg * 8 + e;
            float f = (vg < V_CNT && j < J_CNT) ? lbs_weights[vg * J_CNT + j] : 0.0f;
            val[e] = f2bf(f);
        }
        int chunk = jg ^ (v & 7);
        *(ushort8*)(w_b + v * 128 + chunk * 16) = val;
    }
    if (tid < 192) tr_s[tid] = transl[f0 * 3 + tid];

    // acc -> vp_s [64f][100] bf16 (overlays dead B buffers)
#pragma unroll
    for (int m = 0; m < 2; m++)
#pragma unroll
        for (int nn = 0; nn < 3; nn++)
#pragma unroll
            for (int e = 0; e < 4; e++) {
                int f = wm * 32 + m * 16 + (l >> 4) * 4 + e;
                int col = wn * 48 + nn * 16 + (l & 15);
                vp_s[f * 100 + col] = f2bf(acc[m][nn][e]);
            }
    __syncthreads();

    // -------- GEMM2 per coord c: T[f][v][c*4+rr] = sum_j A_bf[f][c*4+rr][j] * w[v][j] ------
    const unsigned char* Ab = (const unsigned char*)A_bf;
    float res[3][8];
#pragma unroll
    for (int c = 0; c < 3; c++) {
        f32x4 acc2[8];
#pragma unroll
        for (int m = 0; m < 8; m++) acc2[m] = (f32x4){0.f, 0.f, 0.f, 0.f};
#pragma unroll
        for (int ksub = 0; ksub < 2; ksub++) {
            bf16x8 bw;
            {
                int v = wn * 16 + (l & 15);
                int off = v * 128 + ((ksub * 64 + (l >> 4) * 16) ^ ((v & 7) << 4));
                bw = *(const bf16x8*)(w_b + off);
            }
#pragma unroll
            for (int m = 0; m < 8; m++) {
                int row16 = l & 15;
                int f_rel = m * 4 + (row16 >> 2);
                int rr = row16 & 3;
                const unsigned char* asrc = Ab +
                    ((size_t)((f0 + wm * 32 + f_rel) * 12 + c * 4 + rr)) * 128 +
                    ksub * 64 + (l >> 4) * 16;
                bf16x8 af = *(const bf16x8*)asrc;
                acc2[m] = __builtin_amdgcn_mfma_f32_16x16x32_bf16(af, bw, acc2[m], 0, 0, 0);
            }
        }
#pragma unroll
        for (int m = 0; m < 8; m++) {
            int f_rel = wm * 32 + m * 4 + (l >> 4);      // frame within block
            int vloc = wn * 16 + (l & 15);               // vertex within block
            float d0 = bf2f(vp_s[f_rel * 100 + vloc * 3 + 0]);
            float d1 = bf2f(vp_s[f_rel * 100 + vloc * 3 + 1]);
            float d2 = bf2f(vp_s[f_rel * 100 + vloc * 3 + 2]);
            f32x4 tt = acc2[m];
            res[c][m] = tt[0] * d0 + tt[1] * d1 + tt[2] * d2 + tt[3] + tr_s[f_rel * 3 + c];
        }
    }

    // -------- dense epilogue: restage res through LDS, lane-consecutive dword stores ------
    const int olim = N3 - v00 * 3;   // valid dwords within a 96-dword row (tail block)
#pragma unroll
    for (int chunk = 0; chunk < 2; chunk++) {
        __syncthreads();   // all vp_s reads done (chunk 0) / prior copy done (chunk 1)
        if (wm == chunk) {
#pragma unroll
            for (int m = 0; m < 8; m++) {
                int r = m * 4 + (l >> 4);
                int colv = (wn * 16 + (l & 15)) * 3;
#pragma unroll
                for (int c = 0; c < 3; c++)
                    rst[r * 100 + colv + c] = res[c][m];
            }
        }
        __syncthreads();
        size_t base = ((size_t)(f0 + chunk * 32) * V_CNT + v00) * 3;
#pragma unroll
        for (int k = 0; k < 12; k++) {
            int i = tid + k * 256;
            int r = i / 96;
            int o = i - r * 96;
            if (o < olim)
                out[base + (size_t)r * N3 + o] = rst[r * 100 + o];
        }
    }
}

extern "C" void kernel_launch(void* const* d_in, const int* in_sizes, int n_in,
                              void* d_out, int out_size, void* d_ws, size_t ws_size,
                              hipStream_t stream)
{
    const float* body_pose     = (const float*)d_in[0];
    const float* betas         = (const float*)d_in[1];
    const float* global_orient = (const float*)d_in[2];
    const float* transl        = (const float*)d_in[3];
    const float* v_template    = (const float*)d_in[4];
    const float* shapedirs     = (const float*)d_in[5];
    const float* posedirs      = (const float*)d_in[6];
    const float* lbs_weights   = (const float*)d_in[7];
    const float* J_template    = (const float*)d_in[8];
    const float* J_shapedirs   = (const float*)d_in[9];
    const float* odp           = (const float*)d_in[10];
    float* out = (float*)d_out;

    // ws layout: B_pack 31488*512*2 = 32,243,712 | pf_ext 512*512*2 | A_bf 512*12*64*2
    unsigned short* B_pack = (unsigned short*)d_ws;
    unsigned short* pf_ext = (unsigned short*)((char*)d_ws + 32243712);
    unsigned short* A_bf   = (unsigned short*)((char*)d_ws + 32243712 + 524288);

    prep_kernel<<<RPK_BLOCKS + NFRAMES, 256, 0, stream>>>(
        posedirs, shapedirs, v_template, B_pack,
        body_pose, betas, global_orient, J_template, J_shapedirs, odp,
        pf_ext, A_bf);

    gemm_kernel<<<VTILES * FTILES, 256, 0, stream>>>(pf_ext, B_pack, A_bf, lbs_weights,
                                                     transl, out);
}

// Round 17
// 116.341 us; speedup vs baseline: 1.1320x; 1.1320x over previous
//
#include <hip/hip_runtime.h>

#define V_CNT   10475
#define N3      31425      // V*3
#define NPAD    31488      // 164*192
#define J_CNT   55
#define NBETA   10
#define KP      512        // padded K for GEMM1 (486 pf + 10 betas + 1 vt + pad)
#define NFRAMES 512
#define BM      64         // frames per block
#define BNC     192        // columns (verts*3) per block
#define VTILES  164
#define FTILES  8
#define RPK_BLOCKS (492 * 8)   // (NPAD/64) x (KP/64)

typedef __attribute__((ext_vector_type(8))) __bf16 bf16x8;
typedef __attribute__((ext_vector_type(8))) unsigned short ushort8;
typedef __attribute__((ext_vector_type(4))) float f32x4;

__device__ __forceinline__ unsigned short f2bf(float f) {
    unsigned u = __float_as_uint(f);
    u += 0x7fff + ((u >> 16) & 1);
    return (unsigned short)(u >> 16);
}
__device__ __forceinline__ float bf2f(unsigned short s) {
    return __uint_as_float(((unsigned)s) << 16);
}
// global -> LDS direct 16B load. LDS dest must be wave-uniform; lane writes base+lane*16.
__device__ __forceinline__ void gl_lds16(const void* g, void* l) {
    auto gp = (const __attribute__((address_space(1))) unsigned int*)(uintptr_t)g;
    auto lp = (__attribute__((address_space(3))) unsigned int*)(unsigned int)(uintptr_t)l;
    __builtin_amdgcn_global_load_lds(gp, lp, 16, 0, 0);
}

__device__ __constant__ int c_parents[J_CNT] = {
    -1, 0, 0, 0, 1, 2, 3, 4, 5, 6, 7, 8, 9, 9, 9, 12, 13, 14, 16, 17, 18, 19,
    15, 15, 15,
    20, 25, 26, 20, 28, 29, 20, 31, 32, 20, 34, 35, 20, 37, 38,
    21, 40, 41, 21, 43, 44, 21, 46, 47, 21, 49, 50, 21, 52, 53};

// A_pack2 fragment-order layout: 1KB block index = ((((f>>6)*2 + ((f>>5)&1))*8 + ((f>>2)&7))*3 + c)*2 + (j>>5)
// within-block byte = (((f&3)<<2)|rr)*64 + ((j>>3)&3)*16 + (j&7)*2
// GEMM2 lane l reads at laneoff = (l&15)*64 + (l>>4)*16 -> fully contiguous 1KB per wave-load.

// ---------------- prep: repack (blocks [0,RPK_BLOCKS)) + skel (next NFRAMES blocks) -------
__global__ __launch_bounds__(256) void prep_kernel(
    const float* __restrict__ posedirs, const float* __restrict__ shapedirs,
    const float* __restrict__ v_template, unsigned short* __restrict__ B_pack,
    const float* __restrict__ body_pose, const float* __restrict__ betas,
    const float* __restrict__ global_orient, const float* __restrict__ J_template,
    const float* __restrict__ J_shapedirs, const float* __restrict__ odp,
    unsigned short* __restrict__ pf_ext, unsigned short* __restrict__ A_pack2)
{
    const int rb = blockIdx.x;
    const int tid = threadIdx.x;

    __shared__ float R_s[J_CNT][9];
    __shared__ float j_s[J_CNT][3];
    __shared__ float G_s[J_CNT][12];

    if (rb < RPK_BLOCKS) {
        const int n0 = (rb % 492) * 64;
        const int k0 = (rb / 492) * 64;
        const int nl = tid >> 2;
        const int kh = tid & 3;
        const int ng = n0 + nl;
        ushort8 v0, v1;
#pragma unroll
        for (int j = 0; j < 16; j++) {
            int kgl = k0 + kh * 16 + j;
            float v = 0.0f;
            if (ng < N3) {
                if (kgl < 486)       v = posedirs[(size_t)kgl * N3 + ng];
                else if (kgl < 496)  v = shapedirs[ng * NBETA + (kgl - 486)];
                else if (kgl == 496) v = v_template[ng];
            }
            if (j < 8) v0[j] = f2bf(v);
            else       v1[j - 8] = f2bf(v);
        }
        unsigned short* dst = &B_pack[(size_t)(n0 + nl) * KP + k0 + kh * 16];
        *(ushort8*)(dst)     = v0;
        *(ushort8*)(dst + 8) = v1;
        return;
    }

    const int n = rb - RPK_BLOCKS;
    const int lane = tid;

    if (lane < J_CNT) {
        float aa0, aa1, aa2;
        if (lane == 0) {
            aa0 = global_orient[n * 3 + 0];
            aa1 = global_orient[n * 3 + 1];
            aa2 = global_orient[n * 3 + 2];
        } else if (lane < 22) {
            int o = n * 63 + (lane - 1) * 3;
            aa0 = body_pose[o]; aa1 = body_pose[o + 1]; aa2 = body_pose[o + 2];
        } else {
            int o = (lane - 22) * 3;
            aa0 = odp[o]; aa1 = odp[o + 1]; aa2 = odp[o + 2];
        }
        float ang = sqrtf(aa0 * aa0 + aa1 * aa1 + aa2 * aa2 + 1e-12f);
        float inv = 1.0f / ang;
        float ax = aa0 * inv, ay = aa1 * inv, az = aa2 * inv;
        float s = sinf(ang), c = cosf(ang), cc = 1.0f - c;
        float R[9];
        R[0] = c + cc * ax * ax;        R[1] = -s * az + cc * ax * ay;  R[2] = s * ay + cc * ax * az;
        R[3] = s * az + cc * ax * ay;   R[4] = c + cc * ay * ay;        R[5] = -s * ax + cc * ay * az;
        R[6] = -s * ay + cc * ax * az;  R[7] = s * ax + cc * ay * az;   R[8] = c + cc * az * az;
#pragma unroll
        for (int k = 0; k < 9; k++) R_s[lane][k] = R[k];
#pragma unroll
        for (int cd = 0; cd < 3; cd++) {
            float acc = J_template[lane * 3 + cd];
#pragma unroll
            for (int k = 0; k < NBETA; k++)
                acc += betas[n * NBETA + k] * J_shapedirs[(lane * 3 + cd) * NBETA + k];
            j_s[lane][cd] = acc;
        }
        if (lane >= 1) {
#pragma unroll
            for (int e = 0; e < 9; e++)
                pf_ext[n * KP + (lane - 1) * 9 + e] =
                    f2bf(R[e] - ((e == 0 || e == 4 || e == 8) ? 1.0f : 0.0f));
        }
    }
    if (lane == 55) {
#pragma unroll
        for (int b = 0; b < NBETA; b++) pf_ext[n * KP + 486 + b] = f2bf(betas[n * NBETA + b]);
        pf_ext[n * KP + 496] = 0x3F80;
    }
    if (lane == 56) {
        for (int k = 497; k < KP; k++) pf_ext[n * KP + k] = 0;
    }
    __syncthreads();
    if (lane == 0) {
        for (int r = 0; r < 3; r++) {
            G_s[0][r * 4 + 0] = R_s[0][r * 3 + 0];
            G_s[0][r * 4 + 1] = R_s[0][r * 3 + 1];
            G_s[0][r * 4 + 2] = R_s[0][r * 3 + 2];
            G_s[0][r * 4 + 3] = j_s[0][r];
        }
        for (int i = 1; i < J_CNT; i++) {
            int p = c_parents[i];
            float rel0 = j_s[i][0] - j_s[p][0];
            float rel1 = j_s[i][1] - j_s[p][1];
            float rel2 = j_s[i][2] - j_s[p][2];
            for (int r = 0; r < 3; r++) {
                float g0 = G_s[p][r * 4 + 0], g1 = G_s[p][r * 4 + 1], g2 = G_s[p][r * 4 + 2];
                G_s[i][r * 4 + 0] = g0 * R_s[i][0] + g1 * R_s[i][3] + g2 * R_s[i][6];
                G_s[i][r * 4 + 1] = g0 * R_s[i][1] + g1 * R_s[i][4] + g2 * R_s[i][7];
                G_s[i][r * 4 + 2] = g0 * R_s[i][2] + g1 * R_s[i][5] + g2 * R_s[i][8];
                G_s[i][r * 4 + 3] = g0 * rel0 + g1 * rel1 + g2 * rel2 + G_s[p][r * 4 + 3];
            }
        }
    }
    __syncthreads();
    if (lane < 64) {
        float vals[12];
#pragma unroll
        for (int r = 0; r < 12; r++) vals[r] = 0.0f;
        if (lane < J_CNT) {
            const float jx = j_s[lane][0], jy = j_s[lane][1], jz = j_s[lane][2];
#pragma unroll
            for (int r = 0; r < 3; r++) {
                float g0 = G_s[lane][r * 4 + 0], g1 = G_s[lane][r * 4 + 1], g2 = G_s[lane][r * 4 + 2];
                vals[r * 4 + 0] = g0;
                vals[r * 4 + 1] = g1;
                vals[r * 4 + 2] = g2;
                vals[r * 4 + 3] = G_s[lane][r * 4 + 3] - (g0 * jx + g1 * jy + g2 * jz);
            }
        }
        // write fragment-order layout: j = lane (K-dim)
        const int j = lane;
        const int fm = ((n >> 6) * 2 + ((n >> 5) & 1)) * 8 + ((n >> 2) & 7);
        const int jw = ((j >> 3) & 3) * 16 + (j & 7) * 2;   // within-block K bytes
#pragma unroll
        for (int r = 0; r < 12; r++) {
            int cc = r >> 2, rr = r & 3;
            size_t blk = (size_t)((fm * 3 + cc) * 2 + (j >> 5));
            size_t off = blk * 1024 + (size_t)((((n & 3) << 2) | rr) * 64 + jw);
            *(unsigned short*)((unsigned char*)A_pack2 + off) = f2bf(vals[r]);
        }
    }
}

// ---------------- fused GEMM: GEMM1 (R11 pipeline) -> GEMM2 (coalesced A_pack2 loads) ------
__global__ __launch_bounds__(256, 2) void gemm_kernel(
    const unsigned short* __restrict__ pf_ext, const unsigned short* __restrict__ B_pack,
    const unsigned short* __restrict__ A_pack2, const float* __restrict__ lbs_weights,
    const float* __restrict__ transl, float* __restrict__ out)
{
    // LDS map (74496 B -> 2 blocks/CU): as R13.
    __shared__ __align__(128) unsigned char smem[74496];
    unsigned char* pf_b0 = smem;
    unsigned char* pf_b1 = smem + 8192;
    unsigned char* B_b0  = smem + 16384;
    unsigned char* B_b1  = smem + 40960;
    unsigned char* w_b   = smem + 65536;
    float* tr_s          = (float*)(smem + 73728);
    unsigned short* vp_s = (unsigned short*)(smem + 16384);
    float* rst           = (float*)(smem + 41472);

    const int tid = threadIdx.x;
    const int w = tid >> 6, l = tid & 63;
    const int wm = w >> 1, wn = w & 1;

    // XCD co-location decode
    const int bid = blockIdx.x;
    const int group = bid >> 6, gi = bid & 63;
    int vt, ft;
    if (group < 20) { vt = group * 8 + (gi & 7); ft = gi >> 3; }
    else            { vt = 160 + (gi & 3);       ft = gi >> 2; }
    const int f0 = ft * BM;
    const int v00 = vt * 64;
    const int n0c = vt * BNC;

    const unsigned char* pfg = (const unsigned char*)pf_ext + (size_t)f0 * (KP * 2);
    const unsigned char* Bg  = (const unsigned char*)B_pack + (size_t)n0c * (KP * 2);

#define STAGE_KS(ks, pfd, Bd)                                                              \
    {                                                                                      \
        const int kb = (ks) * 128;                                                         \
        _Pragma("unroll")                                                                  \
        for (int i = 0; i < 2; i++) {                                                      \
            int row0 = w * 16 + i * 8;                                                     \
            int row = row0 + (l >> 3);                                                     \
            const unsigned char* src = pfg + (size_t)row * (KP * 2) + kb +                 \
                                       (((l & 7) ^ (l >> 3)) * 16);                        \
            gl_lds16(src, (pfd) + row0 * 128);                                             \
        }                                                                                  \
        _Pragma("unroll")                                                                  \
        for (int i = 0; i < 6; i++) {                                                      \
            int row0 = i * 32 + w * 8;                                                     \
            int row = row0 + (l >> 3);                                                     \
            const unsigned char* src = Bg + (size_t)row * (KP * 2) + kb +                  \
                                       (((l & 7) ^ (l >> 3)) * 16);                        \
            gl_lds16(src, (Bd) + row0 * 128);                                              \
        }                                                                                  \
    }

    // -------- GEMM1 (R11 counted-vmcnt pipeline, verbatim) --------
    f32x4 acc[2][6];
#pragma unroll
    for (int m = 0; m < 2; m++)
#pragma unroll
        for (int nn = 0; nn < 6; nn++) acc[m][nn] = (f32x4){0.f, 0.f, 0.f, 0.f};

    STAGE_KS(0, pf_b0, B_b0);
    STAGE_KS(1, pf_b1, B_b1);
    asm volatile("s_waitcnt vmcnt(8)" ::: "memory");
    __builtin_amdgcn_sched_barrier(0);
    __builtin_amdgcn_s_barrier();

#pragma unroll
    for (int ks = 0; ks < 8; ks++) {
        unsigned char* pfc = (ks & 1) ? pf_b1 : pf_b0;
        unsigned char* Bc  = (ks & 1) ? B_b1 : B_b0;
#pragma unroll
        for (int ksub = 0; ksub < 2; ksub++) {
            bf16x8 a[2], b[6];
#pragma unroll
            for (int m = 0; m < 2; m++) {
                int f = wm * 32 + m * 16 + (l & 15);
                int off = f * 128 + ((ksub * 64 + (l >> 4) * 16) ^ ((f & 7) << 4));
                a[m] = *(const bf16x8*)(pfc + off);
            }
#pragma unroll
            for (int nn = 0; nn < 6; nn++) {
                int col = wn * 96 + nn * 16 + (l & 15);
                int off = col * 128 + ((ksub * 64 + (l >> 4) * 16) ^ ((col & 7) << 4));
                b[nn] = *(const bf16x8*)(Bc + off);
            }
#pragma unroll
            for (int m = 0; m < 2; m++)
#pragma unroll
                for (int nn = 0; nn < 6; nn++)
                    acc[m][nn] = __builtin_amdgcn_mfma_f32_16x16x32_bf16(a[m], b[nn], acc[m][nn], 0, 0, 0);
        }
        __builtin_amdgcn_sched_barrier(0);
        __builtin_amdgcn_s_barrier();
        if (ks < 6) {
            STAGE_KS(ks + 2, pfc, Bc);
        }
        if (ks < 7) {
            if (ks < 6) asm volatile("s_waitcnt vmcnt(8)" ::: "memory");
            else        asm volatile("s_waitcnt vmcnt(0)" ::: "memory");
            __builtin_amdgcn_sched_barrier(0);
            __builtin_amdgcn_s_barrier();
        }
    }
#undef STAGE_KS

    // stage lbs weights tile -> w_b (deferred), transl -> tr_s
    {
        int v = tid >> 2, jg = tid & 3;
        int vg = v00 + v;
#pragma unroll
        for (int h = 0; h < 2; h++) {
            ushort8 val;
#pragma unroll
            for (int e = 0; e < 8; e++) {
                int j = jg * 16 + h * 8 + e;
                float f = (vg < V_CNT && j < J_CNT) ? lbs_weights[vg * J_CNT + j] : 0.0f;
                val[e] = f2bf(f);
            }
            int chunk = (jg * 2 + h) ^ (v & 7);
            *(ushort8*)(w_b + v * 128 + chunk * 16) = val;
        }
    }
    if (tid < 192) tr_s[tid] = transl[f0 * 3 + tid];

    // acc -> vp_s [64f][196] bf16 (overlays B_b[0])
#pragma unroll
    for (int m = 0; m < 2; m++)
#pragma unroll
        for (int nn = 0; nn < 6; nn++)
#pragma unroll
            for (int e = 0; e < 4; e++) {
                int f = wm * 32 + m * 16 + (l >> 4) * 4 + e;
                int col = wn * 96 + nn * 16 + (l & 15);
                vp_s[f * 196 + col] = f2bf(acc[m][nn][e]);
            }
    __syncthreads();

    // -------- GEMM2: A-frags from fragment-order A_pack2 (1KB contiguous per wave-load) ----
    const unsigned char* A2 = (const unsigned char*)A_pack2 +
                              (size_t)((ft * 2 + wm) * 8) * (3 * 2 * 1024);
    const int laneoff = (l & 15) * 64 + (l >> 4) * 16;
    float res[3][8][2];
#pragma unroll
    for (int c = 0; c < 3; c++) {
        f32x4 acc2[8][2];
#pragma unroll
        for (int m = 0; m < 8; m++)
#pragma unroll
            for (int nn = 0; nn < 2; nn++) acc2[m][nn] = (f32x4){0.f, 0.f, 0.f, 0.f};
#pragma unroll
        for (int ksub = 0; ksub < 2; ksub++) {
            bf16x8 bw[2];
#pragma unroll
            for (int nn = 0; nn < 2; nn++) {
                int v = wn * 32 + nn * 16 + (l & 15);
                int off = v * 128 + ((ksub * 64 + (l >> 4) * 16) ^ ((v & 7) << 4));
                bw[nn] = *(const bf16x8*)(w_b + off);
            }
#pragma unroll
            for (int m = 0; m < 8; m++) {
                const unsigned char* asrc = A2 +
                    (size_t)((m * 3 + c) * 2 + ksub) * 1024 + laneoff;
                bf16x8 af = *(const bf16x8*)asrc;
                acc2[m][0] = __builtin_amdgcn_mfma_f32_16x16x32_bf16(af, bw[0], acc2[m][0], 0, 0, 0);
                acc2[m][1] = __builtin_amdgcn_mfma_f32_16x16x32_bf16(af, bw[1], acc2[m][1], 0, 0, 0);
            }
        }
#pragma unroll
        for (int m = 0; m < 8; m++)
#pragma unroll
            for (int nn = 0; nn < 2; nn++) {
                int f_rel = wm * 32 + m * 4 + (l >> 4);
                int vloc = wn * 32 + nn * 16 + (l & 15);
                float d0 = bf2f(vp_s[f_rel * 196 + vloc * 3 + 0]);
                float d1 = bf2f(vp_s[f_rel * 196 + vloc * 3 + 1]);
                float d2 = bf2f(vp_s[f_rel * 196 + vloc * 3 + 2]);
                f32x4 tt = acc2[m][nn];
                res[c][m][nn] = tt[0] * d0 + tt[1] * d1 + tt[2] * d2 + tt[3] + tr_s[f_rel * 3 + c];
            }
    }

    // -------- dense epilogue (R13 verbatim) --------
    const int olim = N3 - v00 * 3;
#pragma unroll
    for (int chunk = 0; chunk < 2; chunk++) {
        __syncthreads();
        if (wm == chunk) {
#pragma unroll
            for (int m = 0; m < 8; m++)
#pragma unroll
                for (int nn = 0; nn < 2; nn++) {
                    int r = m * 4 + (l >> 4);
                    int colv = (wn * 32 + nn * 16 + (l & 15)) * 3;
#pragma unroll
                    for (int c = 0; c < 3; c++)
                        rst[r * 200 + colv + c] = res[c][m][nn];
                }
        }
        __syncthreads();
        size_t base = ((size_t)(f0 + chunk * 32) * V_CNT + v00) * 3;
#pragma unroll
        for (int k = 0; k < 24; k++) {
            int i = tid + k * 256;
            int r = i / 192;
            int o = i - r * 192;
            if (o < olim)
                out[base + (size_t)r * N3 + o] = rst[r * 200 + o];
        }
    }
}

extern "C" void kernel_launch(void* const* d_in, const int* in_sizes, int n_in,
                              void* d_out, int out_size, void* d_ws, size_t ws_size,
                              hipStream_t stream)
{
    const float* body_pose     = (const float*)d_in[0];
    const float* betas         = (const float*)d_in[1];
    const float* global_orient = (const float*)d_in[2];
    const float* transl        = (const float*)d_in[3];
    const float* v_template    = (const float*)d_in[4];
    const float* shapedirs     = (const float*)d_in[5];
    const float* posedirs      = (const float*)d_in[6];
    const float* lbs_weights   = (const float*)d_in[7];
    const float* J_template    = (const float*)d_in[8];
    const float* J_shapedirs   = (const float*)d_in[9];
    const float* odp           = (const float*)d_in[10];
    float* out = (float*)d_out;

    // ws layout: B_pack 31488*512*2 = 32,243,712 | pf_ext 512*512*2 | A_pack2 512*12*64*2
    unsigned short* B_pack   = (unsigned short*)d_ws;
    unsigned short* pf_ext   = (unsigned short*)((char*)d_ws + 32243712);
    unsigned short* A_pack2  = (unsigned short*)((char*)d_ws + 32243712 + 524288);

    prep_kernel<<<RPK_BLOCKS + NFRAMES, 256, 0, stream>>>(
        posedirs, shapedirs, v_template, B_pack,
        body_pose, betas, global_orient, J_template, J_shapedirs, odp,
        pf_ext, A_pack2);

    gemm_kernel<<<VTILES * FTILES, 256, 0, stream>>>(pf_ext, B_pack, A_pack2, lbs_weights,
                                                     transl, out);
}